// Round 1
// baseline (9527.117 us; speedup 1.0000x reference)
//
#include <hip/hip_runtime.h>
#include <math.h>
#include <string.h>

// Problem constants (mirror reference)
#define B_   128
#define NT_  200
#define NX_  256
#define NG_  12

static const double C_D = (255.0 * 255.0) / 199.0;   // eps*dt/dx^2, dt=1/199, dx=1/255
#define INV_DT_F 199.0f
#define DT_F (1.0f / 199.0f)

// ---------------- host-side matrix construction ----------------
// Device matrix layout: Mdev[k*256+j] such that y_new[j] = sum_k y[k]*Mdev[k*256+j]
// Reference uses y @ M with M = inv(I - c*A).T, so Mdev[k][j] = inv[j][k].

static double g_A[256][256];
static double g_Bm[256][256];
static double g_aug[256][512];
static float  g_M[2 * 256 * 256];   // [0]: periodic (M), [1]: Dirichlet (M_C)

static void build_and_invert(int bc_dirichlet, float* outT) {
    memset(g_A, 0, sizeof(g_A));
    for (int i = 0; i < 256; i++) g_A[i][i] = -2.0;
    for (int i = 0; i < 255; i++) { g_A[i][i + 1] = 1.0; g_A[i + 1][i] = 1.0; }
    if (bc_dirichlet) {
        g_A[0][0] = g_A[0][1] = g_A[1][0] = 0.0;
        g_A[255][255] = g_A[255][254] = g_A[254][255] = 0.0;
    } else { // periodic per reference
        g_A[255][1] = 1.0;
        g_A[0][254] = 1.0;
    }
    for (int i = 0; i < 256; i++)
        for (int j = 0; j < 256; j++)
            g_Bm[i][j] = ((i == j) ? 1.0 : 0.0) - C_D * g_A[i][j];

    // Gauss-Jordan (diagonally dominant -> no pivoting)
    for (int i = 0; i < 256; i++) {
        for (int j = 0; j < 256; j++) g_aug[i][j] = g_Bm[i][j];
        for (int j = 0; j < 256; j++) g_aug[i][256 + j] = (i == j) ? 1.0 : 0.0;
    }
    for (int k = 0; k < 256; k++) {
        double inv = 1.0 / g_aug[k][k];
        for (int j = 0; j < 512; j++) g_aug[k][j] *= inv;
        for (int i = 0; i < 256; i++) {
            if (i == k) continue;
            double f = g_aug[i][k];
            if (f == 0.0) continue;
            for (int j = 0; j < 512; j++) g_aug[i][j] -= f * g_aug[k][j];
        }
    }
    // outT[k*256+j] = inv[j][k]
    for (int k = 0; k < 256; k++)
        for (int j = 0; j < 256; j++)
            outT[k * 256 + j] = (float)g_aug[j][256 + k];
}

// ---------------- kernels ----------------

// Fill: dW into channel 0 everywhere; t=0 row: ch1=U0, ch2..11=0
__global__ void k_fill(const float* __restrict__ W, const float* __restrict__ U0,
                       float* __restrict__ out) {
    int tid = blockIdx.x * 256 + threadIdx.x;     // == (b*200+t)*256+x
    int x = tid & 255;
    int t = (tid >> 8) % 200;
    int b = tid / (256 * 200);
    float w = W[tid];
    float dw = 0.f;
    if (t > 0) dw = (w - W[tid - 256]) * INV_DT_F;
    size_t ob = (size_t)tid * NG_;
    out[ob] = dw;
    if (t == 0) {
        out[ob + 1] = U0[b * 256 + x];
#pragma unroll
        for (int g = 2; g < 12; g++) out[ob + g] = 0.f;
    }
}

__device__ __forceinline__ float tmp_val(int node, const float* __restrict__ W,
                                         const float* __restrict__ out,
                                         int b, int i, int j) {
    size_t base = ((size_t)(b * NT_ + i) * NX_ + j);
    size_t ob = base * NG_;
    float dw;
    switch (node) {
        case 2:  return (W[base] - W[base - 256]) * INV_DT_F;
        case 4:  dw = (W[base] - W[base - 256]) * INV_DT_F; return dw * dw;
        case 3:  return out[ob + 1];
        case 5:  dw = (W[base] - W[base - 256]) * INV_DT_F; return dw * out[ob + 1];
        case 6:  { float f = out[ob + 2]; return f * f; }
        case 7:  return out[ob + 2] * out[ob + 1];
        case 8:  { float f = out[ob + 2]; return f * f * f; }
        case 9:  dw = (W[base] - W[base - 256]) * INV_DT_F; return dw * out[ob + 2];
        case 10: { float c1 = out[ob + 1]; return c1 * c1; }
        default: return out[ob + 4] * out[ob + 2];  // node 11: f4*f2
    }
}

// One block per (batch, scan). 512 threads: thread (h=tid>>8, j=tid&255) owns
// rows [128h,128h+128) of M's column j in registers. State z[256] in LDS.
__global__ __launch_bounds__(512, 2) void k_scan(const float* __restrict__ W,
                                                 const float* __restrict__ U0,
                                                 const float* __restrict__ Mws,
                                                 float* __restrict__ out, int phase) {
    int b = blockIdx.x;
    int sn = blockIdx.y;
    int node;
    if (phase == 0) {
        node = (sn == 0) ? 1 : ((sn == 1) ? 2 : 4);
    } else {
        const int L[8] = {3, 5, 6, 7, 8, 9, 10, 11};
        node = L[sn];
    }
    const float* M = (node == 1) ? (Mws + 65536) : Mws;  // ic uses Dirichlet matrix

    int tid = threadIdx.x;
    int h = tid >> 8;
    int j = tid & 255;

    // register-cache half a column of M (reused 199x)
    float m[128];
#pragma unroll
    for (int k = 0; k < 128; k++) m[k] = M[(size_t)(h * 128 + k) * 256 + j];

    __shared__ __align__(16) float z[256];
    __shared__ float pb[256];

    if (h == 0) {
        if (node == 1) z[j] = U0[b * 256 + j];
        else           z[j] = tmp_val(node, W, out, b, 1, j) * DT_F;
    }
    __syncthreads();

    for (int i = 1; i < NT_; ++i) {
        // prefetch next step's forcing term (global loads overlap the dot)
        float tn = 0.f;
        if (h == 0 && node != 1 && i < NT_ - 1)
            tn = tmp_val(node, W, out, b, i + 1, j);

        float acc = 0.f;
        const float4* zv = (const float4*)(&z[h * 128]);
#pragma unroll
        for (int k4 = 0; k4 < 32; k4++) {
            float4 zz = zv[k4];
            acc += m[4 * k4 + 0] * zz.x;
            acc += m[4 * k4 + 1] * zz.y;
            acc += m[4 * k4 + 2] * zz.z;
            acc += m[4 * k4 + 3] * zz.w;
        }
        if (h) pb[j] = acc;
        __syncthreads();
        if (!h) {
            float y = acc + pb[j];
            out[((size_t)(b * NT_ + i) * NX_ + j) * NG_ + node] = y;
            z[j] = (node == 1) ? y : (y + tn * DT_F);
        }
        __syncthreads();
    }
}

// ---------------- launch ----------------
extern "C" void kernel_launch(void* const* d_in, const int* in_sizes, int n_in,
                              void* d_out, int out_size, void* d_ws, size_t ws_size,
                              hipStream_t stream) {
    const float* W  = (const float*)d_in[0];
    const float* U0 = (const float*)d_in[1];
    float* out = (float*)d_out;
    float* Mws = (float*)d_ws;

    // Recompute deterministically every call (host code runs at capture time only)
    build_and_invert(0, g_M);            // periodic -> M
    build_and_invert(1, g_M + 65536);    // Dirichlet -> M_C
    hipMemcpyAsync(Mws, g_M, sizeof(g_M), hipMemcpyHostToDevice, stream);

    k_fill<<<dim3(B_ * NT_), 256, 0, stream>>>(W, U0, out);
    k_scan<<<dim3(B_, 3), 512, 0, stream>>>(W, U0, Mws, out, 0);
    k_scan<<<dim3(B_, 8), 512, 0, stream>>>(W, U0, Mws, out, 1);
}

// Round 2
// 1469.126 us; speedup vs baseline: 6.4849x; 6.4849x over previous
//
#include <hip/hip_runtime.h>

#define NTT 200
#define NXX 256
#define NB  128
#define NGC 12
#define DTF  (1.0f/199.0f)
#define IDTF 199.0f

// ======================= device-side matrix construction =======================
// B = I - c*A is tridiagonal (+rank-2 periodic corners). Columns of B^-1 via
// fp64 Thomas solves; periodic handled by Woodbury rank-2 correction.
// Device layout: Mdev[k*256+j] = Binv[j][k]  (so y_new[j] = sum_k y[k]*Mdev[k][j]).

__global__ void k_mats1(double* __restrict__ Gd, float* __restrict__ McD) {
    const double c = 65025.0 / 199.0;           // eps*dt/dx^2
    const double bd = 1.0 + 2.0 * c, a = -c;    // diag, offdiag of I - c*tri
    __shared__ double cp[256], invd[256];
    int tid = threadIdx.x;
    if (tid == 0) {
        double prev = 0.0;
        for (int i = 0; i < 256; i++) {
            double den = bd - a * prev;
            double ci = a / den;
            cp[i] = ci; invd[i] = 1.0 / den; prev = ci;
        }
    }
    __syncthreads();
    double x[256];
    if (tid < 256) {
        // periodic base T0 (size 256): column tid of G = T0^-1
        int jc = tid;
        double dp = 0.0;
        for (int i = 0; i < 256; i++) {
            double r = (i == jc) ? 1.0 : 0.0;
            dp = (r - a * dp) * invd[i];
            x[i] = dp;
        }
        for (int i = 254; i >= 0; i--) x[i] -= cp[i] * x[i + 1];
        for (int i = 0; i < 256; i++) Gd[jc * 256 + i] = x[i];
    } else {
        // Dirichlet: blockdiag(1, S, 1), S = interior 254x254 same coeffs
        int jc = tid - 256;
        if (jc == 0 || jc == 255) {
            for (int k = 0; k < 256; k++) McD[k * 256 + jc] = (k == jc) ? 1.f : 0.f;
        } else {
            int n = 254, jj = jc - 1;
            double dp = 0.0;
            for (int i = 0; i < n; i++) {
                double r = (i == jj) ? 1.0 : 0.0;
                dp = (r - a * dp) * invd[i];
                x[i] = dp;
            }
            for (int i = n - 2; i >= 0; i--) x[i] -= cp[i] * x[i + 1];
            McD[0 * 256 + jc] = 0.f; McD[255 * 256 + jc] = 0.f;
            for (int k = 1; k < 255; k++) McD[k * 256 + jc] = (float)x[k - 1];
        }
    }
}

__global__ void k_mats2(const double* __restrict__ Gd, float* __restrict__ Mper) {
    const double c = 65025.0 / 199.0;
    int k = blockIdx.x, j = threadIdx.x;
    // B_P = T0 + U V^T, U = [-c e255, -c e0], V = [e1, e254]
    double G1_255 = Gd[256 + 255],     G1_0 = Gd[256 + 0];
    double G254_255 = Gd[254 * 256 + 255], G254_0 = Gd[254 * 256 + 0];
    double K00 = 1.0 - c * G1_255, K01 = -c * G1_0;
    double K10 = -c * G254_255,    K11 = 1.0 - c * G254_0;
    double id = 1.0 / (K00 * K11 - K01 * K10);
    double Ki00 = K11 * id, Ki01 = -K01 * id, Ki10 = -K10 * id, Ki11 = K00 * id;
    double g1k = Gd[256 + k], g254k = Gd[254 * 256 + k];
    double gjk = Gd[j * 256 + k], gj255 = Gd[j * 256 + 255], gj0 = Gd[j * 256 + 0];
    double corr = c * (gj255 * (Ki00 * g1k + Ki01 * g254k) +
                       gj0   * (Ki10 * g1k + Ki11 * g254k));
    Mper[k * 256 + j] = (float)(gjk + corr);
}

// ======================= forcing terms =======================
template<bool CONT>
__device__ __forceinline__ float forcing(int node, const float* __restrict__ W,
                                         const float* __restrict__ cont,
                                         const float* __restrict__ out,
                                         int b, int i, int j) {
    int widx = (b * NTT + i) * NXX + j;
    float dw;
    if (CONT) {
        size_t cb = (size_t)b * NTT * NXX + (size_t)i * NXX + j;
        const size_t CS = (size_t)NB * NTT * NXX;
        switch (node) {
            case 2:  return (W[widx] - W[widx - NXX]) * IDTF;
            case 4:  dw = (W[widx] - W[widx - NXX]) * IDTF; return dw * dw;
            case 3:  return cont[cb];                              // ic (slot0)
            case 5:  dw = (W[widx] - W[widx - NXX]) * IDTF; return dw * cont[cb];
            case 6:  { float f = cont[CS + cb]; return f * f; }    // f2 (slot1)
            case 7:  return cont[CS + cb] * cont[cb];
            case 8:  { float f = cont[CS + cb]; return f * f * f; }
            case 9:  dw = (W[widx] - W[widx - NXX]) * IDTF; return dw * cont[CS + cb];
            case 10: { float f = cont[cb]; return f * f; }
            default: return cont[3 * CS + cb] * cont[CS + cb];     // f4*f2
        }
    } else {
        size_t ob = (size_t)widx * NGC;
        switch (node) {
            case 2:  return (W[widx] - W[widx - NXX]) * IDTF;
            case 4:  dw = (W[widx] - W[widx - NXX]) * IDTF; return dw * dw;
            case 3:  return out[ob + 1];
            case 5:  dw = (W[widx] - W[widx - NXX]) * IDTF; return dw * out[ob + 1];
            case 6:  { float f = out[ob + 2]; return f * f; }
            case 7:  return out[ob + 2] * out[ob + 1];
            case 8:  { float f = out[ob + 2]; return f * f * f; }
            case 9:  dw = (W[widx] - W[widx - NXX]) * IDTF; return dw * out[ob + 2];
            case 10: { float f = out[ob + 1]; return f * f; }
            default: return out[ob + 4] * out[ob + 2];
        }
    }
}

// ======================= scan kernel =======================
// Block: 512 threads, (h = tid>>8) owns K-half, j = tid&255 owns column j.
// m[128] = half of M column j, pinned in VGPRs. GROUP batches per block.
template<int GROUP, int PHASE, bool CONT>
__global__ __launch_bounds__(512, 2) void k_scan(const float* __restrict__ W,
        const float* __restrict__ U0, const float* __restrict__ Mws,
        float* __restrict__ out, float* __restrict__ cont) {
    int node;
    if (PHASE == 0) { const int L[3] = {1, 2, 4}; node = L[blockIdx.y]; }
    else            { const int L[8] = {3, 5, 6, 7, 8, 9, 10, 11}; node = L[blockIdx.y]; }
    const float* M = (node == 1) ? (Mws + 65536) : Mws;   // ic uses Dirichlet
    int b0 = blockIdx.x * GROUP;
    int tid = threadIdx.x, h = tid >> 8, j = tid & 255;

    float m[128];
#pragma unroll
    for (int k = 0; k < 128; k++) m[k] = M[(h * 128 + k) * 256 + j];
#pragma unroll
    for (int k = 0; k < 128; k++) asm volatile("" : "+v"(m[k]));  // pin in VGPRs

    __shared__ __align__(16) float z[GROUP][256];
    __shared__ float pb[GROUP][256];

    if (h == 0) {
#pragma unroll
        for (int g = 0; g < GROUP; g++) {
            if (node == 1) z[g][j] = U0[(b0 + g) * 256 + j];
            else z[g][j] = forcing<CONT>(node, W, cont, out, b0 + g, 1, j) * DTF;
        }
    }
    __syncthreads();

    for (int i = 1; i < NTT; i++) {
        float tn[GROUP];
#pragma unroll
        for (int g = 0; g < GROUP; g++) tn[g] = 0.f;
        if (h == 0 && node != 1 && i + 1 < NTT) {
#pragma unroll
            for (int g = 0; g < GROUP; g++)
                tn[g] = forcing<CONT>(node, W, cont, out, b0 + g, i + 1, j);
        }
        float acc[GROUP];
#pragma unroll
        for (int g = 0; g < GROUP; g++) acc[g] = 0.f;
#pragma unroll
        for (int k4 = 0; k4 < 32; k4++) {
#pragma unroll
            for (int g = 0; g < GROUP; g++) {
                float4 zz = *(const float4*)&z[g][h * 128 + 4 * k4];
                acc[g] = fmaf(m[4 * k4 + 0], zz.x, acc[g]);
                acc[g] = fmaf(m[4 * k4 + 1], zz.y, acc[g]);
                acc[g] = fmaf(m[4 * k4 + 2], zz.z, acc[g]);
                acc[g] = fmaf(m[4 * k4 + 3], zz.w, acc[g]);
            }
        }
        if (h == 1) {
#pragma unroll
            for (int g = 0; g < GROUP; g++) pb[g][j] = acc[g];
        }
        __syncthreads();
        if (h == 0) {
#pragma unroll
            for (int g = 0; g < GROUP; g++) {
                float y = acc[g] + pb[g][j];
                if (CONT)
                    cont[(((size_t)(node - 1) * NB + (b0 + g)) * NTT + i) * NXX + j] = y;
                else
                    out[((size_t)((b0 + g) * NTT + i) * NXX + j) * NGC + node] = y;
                z[g][j] = (node == 1) ? y : fmaf(tn[g], DTF, y);
            }
        }
        __syncthreads();
    }
}

// ======================= output assembly (CONT path) =======================
__global__ void k_out(const float* __restrict__ W, const float* __restrict__ U0,
                      const float* __restrict__ cont, float* __restrict__ out) {
    int t = blockIdx.x, b = blockIdx.y, x = threadIdx.x;
    int idx = (b * NTT + t) * NXX + x;
    float v[12];
    float dw = 0.f;
    if (t) dw = (W[idx] - W[idx - NXX]) * IDTF;
    v[0] = dw;
    if (t) {
        size_t cb = (size_t)b * NTT * NXX + (size_t)t * NXX + x;
        const size_t CS = (size_t)NB * NTT * NXX;
#pragma unroll
        for (int n = 1; n < 12; n++) v[n] = cont[(size_t)(n - 1) * CS + cb];
    } else {
        v[1] = U0[b * NXX + x];
#pragma unroll
        for (int n = 2; n < 12; n++) v[n] = 0.f;
    }
    float4* o = (float4*)(out + (size_t)idx * 12);
    o[0] = make_float4(v[0], v[1], v[2], v[3]);
    o[1] = make_float4(v[4], v[5], v[6], v[7]);
    o[2] = make_float4(v[8], v[9], v[10], v[11]);
}

// fallback fill (non-CONT path)
__global__ void k_fill(const float* __restrict__ W, const float* __restrict__ U0,
                       float* __restrict__ out) {
    int tid = blockIdx.x * 256 + threadIdx.x;
    int x = tid & 255;
    int t = (tid >> 8) % NTT;
    int b = tid / (NXX * NTT);
    float dw = 0.f;
    if (t > 0) dw = (W[tid] - W[tid - NXX]) * IDTF;
    size_t ob = (size_t)tid * NGC;
    out[ob] = dw;
    if (t == 0) {
        out[ob + 1] = U0[b * 256 + x];
#pragma unroll
        for (int g = 2; g < 12; g++) out[ob + g] = 0.f;
    }
}

// ======================= launch =======================
extern "C" void kernel_launch(void* const* d_in, const int* in_sizes, int n_in,
                              void* d_out, int out_size, void* d_ws, size_t ws_size,
                              hipStream_t stream) {
    const float* W  = (const float*)d_in[0];
    const float* U0 = (const float*)d_in[1];
    float* out = (float*)d_out;

    double* Gd  = (double*)d_ws;                         // 512 KB fp64 T0^-1
    float*  Mper = (float*)((char*)d_ws + (512 << 10));  // 256 KB
    float*  McD  = (float*)((char*)d_ws + (768 << 10));  // 256 KB (= Mper+65536)
    float*  cont = (float*)((char*)d_ws + (1 << 20));    // 11 * 26.2 MB

    size_t need = (size_t)(1 << 20) + 11ull * NB * NTT * NXX * 4;
    bool cont_ok = ws_size >= need;

    k_mats1<<<1, 512, 0, stream>>>(Gd, McD);
    k_mats2<<<256, 256, 0, stream>>>(Gd, Mper);

    if (cont_ok) {
        k_scan<2, 0, true><<<dim3(64, 3), 512, 0, stream>>>(W, U0, Mper, out, cont);
        k_scan<4, 1, true><<<dim3(32, 8), 512, 0, stream>>>(W, U0, Mper, out, cont);
        k_out<<<dim3(NTT, NB), 256, 0, stream>>>(W, U0, cont, out);
    } else {
        k_fill<<<NB * NTT, 256, 0, stream>>>(W, U0, out);
        k_scan<2, 0, false><<<dim3(64, 3), 512, 0, stream>>>(W, U0, Mper, out, cont);
        k_scan<4, 1, false><<<dim3(32, 8), 512, 0, stream>>>(W, U0, Mper, out, cont);
    }
}